// Round 1
// 766.190 us; speedup vs baseline: 1.0204x; 1.0204x over previous
//
#include <hip/hip_runtime.h>
#include <hip/hip_fp16.h>

typedef _Float16 f16;
typedef __attribute__((ext_vector_type(8))) _Float16 f16x8;
typedef __attribute__((ext_vector_type(4))) _Float16 f16x4;
typedef __attribute__((ext_vector_type(4))) float f32x4;

#define NSEG 50000
#define DIM 128
#define LDST 136  // f16 elems per LDS row: 128 + 8 pad

#define MFMA16(a, b, c) __builtin_amdgcn_mfma_f32_16x16x32_f16((a), (b), (c), 0, 0, 0)

// ---------------- zero-fill (graph-capture-safe), two buffers in one launch ----------
__global__ void zero2_kernel(float4* __restrict__ a, int n4a,
                             float4* __restrict__ b, int n4b) {
    int i = blockIdx.x * blockDim.x + threadIdx.x;
    float4 z = make_float4(0.f, 0.f, 0.f, 0.f);
    if (i < n4a) {
        a[i] = z;
    } else {
        int j = i - n4a;
        if (j < n4b) b[j] = z;
    }
}

// ---------------- prepack: W^T in A-fragment order ----------------
// A-frag (16x16x32): lane holds A[m'][k], m' = tm*16 + (lane&15),
// k = kt*32 + (lane>>4)*8 + j (j=0..7 contiguous).
// pack[q][((tm*4+kt)*64+lane)*8 + j] = (f16) W[k][m']   (W row-major [k][n])
__global__ void prepack_kernel(const float* __restrict__ w0, const float* __restrict__ w1,
                               const float* __restrict__ w2, const float* __restrict__ w3,
                               f16* __restrict__ packs) {
    int gid = blockIdx.x * blockDim.x + threadIdx.x;  // 8192 threads
    int q = gid >> 11;
    int r = gid & 2047;
    int tm = r >> 8;
    int kt = (r >> 6) & 3;
    int lane = r & 63;
    const float* W = (q == 0) ? w0 : (q == 1) ? w1 : (q == 2) ? w2 : w3;
    int mp = tm * 16 + (lane & 15);
    int kb = kt * 32 + ((lane >> 4) & 3) * 8;
    f16* dst = packs + q * 16384 + ((size_t)((tm * 4 + kt) * 64 + lane)) * 8;
#pragma unroll
    for (int j = 0; j < 8; ++j)
        dst[j] = (f16)W[(size_t)(kb + j) * DIM + mp];
}

// ---------------- phi MLP + fused sorted-segment scatter-sum ----------------
// launch_bounds(256,4): VGPR<=128 -> 4 blocks/CU (LDS 4*35.3KB = 141KB <= 160KB)
__global__ __launch_bounds__(256, 4)
void phi_scatter_kernel(const float* __restrict__ x, const int* __restrict__ batch,
                        const f16* __restrict__ pack1, const f16* __restrict__ pack2,
                        const float* __restrict__ b1, const float* __restrict__ b2,
                        float* __restrict__ seg_sum, float* __restrict__ counts, int N) {
    __shared__ f16 buf[128 * LDST];
    __shared__ int seg_s[128];

    int tid = threadIdx.x;
    int wave = tid >> 6, lane = tid & 63, g = lane >> 4, ln = lane & 15;
    long long r0 = (long long)blockIdx.x * 128;
    int nvalid = min(128, N - (int)r0);

    // stage x (fp32 global) -> f16 LDS [row][k]
#pragma unroll
    for (int i = 0; i < 16; ++i) {
        int flat = i * 1024 + tid * 4;
        int row = flat >> 7, col = flat & 127;
        float4 v = make_float4(0.f, 0.f, 0.f, 0.f);
        if (row < nvalid) v = *(const float4*)(x + (r0 + row) * DIM + col);
        f16x4 h;
        h[0] = (f16)v.x; h[1] = (f16)v.y; h[2] = (f16)v.z; h[3] = (f16)v.w;
        *(f16x4*)(buf + row * LDST + col) = h;
    }
    if (tid < 128) {
        int s = 0;
        if (tid < nvalid) {
            s = batch[r0 + tid];                 // int32 per harness convention
            s = (s < 0) ? 0 : ((s >= NSEG) ? NSEG - 1 : s);  // fault insurance
        } else {
            s = -1;
        }
        seg_s[tid] = s;
    }
    __syncthreads();

    int tm0 = wave * 2;
    f32x4 acc[2][8];
#pragma unroll
    for (int a = 0; a < 2; ++a)
#pragma unroll
        for (int t = 0; t < 8; ++t) acc[a][t] = (f32x4){0.f, 0.f, 0.f, 0.f};

    // GEMM1: h1^T = W1^T * x^T   (M=hidden, N=rows)
#pragma unroll
    for (int kt = 0; kt < 4; ++kt) {
        f16x8 a0 = *(const f16x8*)(pack1 + ((size_t)((tm0 + 0) * 4 + kt) * 64 + lane) * 8);
        f16x8 a1 = *(const f16x8*)(pack1 + ((size_t)((tm0 + 1) * 4 + kt) * 64 + lane) * 8);
#pragma unroll
        for (int tn = 0; tn < 8; ++tn) {
            f16x8 b = *(const f16x8*)(buf + (tn * 16 + ln) * LDST + kt * 32 + g * 8);
            acc[0][tn] = MFMA16(a0, b, acc[0][tn]);
            acc[1][tn] = MFMA16(a1, b, acc[1][tn]);
        }
    }
    __syncthreads();

    // epilogue1: relu(c + b1[hidden]) -> buf[row][hidden] (B-operand layout for GEMM2)
#pragma unroll
    for (int a = 0; a < 2; ++a) {
        int tm = tm0 + a;
        float4 bv = *(const float4*)(b1 + tm * 16 + g * 4);
#pragma unroll
        for (int tn = 0; tn < 8; ++tn) {
            f32x4 c = acc[a][tn];
            f16x4 h;
            h[0] = (f16)fmaxf(c[0] + bv.x, 0.f);
            h[1] = (f16)fmaxf(c[1] + bv.y, 0.f);
            h[2] = (f16)fmaxf(c[2] + bv.z, 0.f);
            h[3] = (f16)fmaxf(c[3] + bv.w, 0.f);
            *(f16x4*)(buf + (tn * 16 + ln) * LDST + tm * 16 + g * 4) = h;
        }
    }
    __syncthreads();

    // GEMM2: h^T = W2^T * h1^T
#pragma unroll
    for (int a = 0; a < 2; ++a)
#pragma unroll
        for (int t = 0; t < 8; ++t) acc[a][t] = (f32x4){0.f, 0.f, 0.f, 0.f};
#pragma unroll
    for (int kt = 0; kt < 4; ++kt) {
        f16x8 a0 = *(const f16x8*)(pack2 + ((size_t)((tm0 + 0) * 4 + kt) * 64 + lane) * 8);
        f16x8 a1 = *(const f16x8*)(pack2 + ((size_t)((tm0 + 1) * 4 + kt) * 64 + lane) * 8);
#pragma unroll
        for (int tn = 0; tn < 8; ++tn) {
            f16x8 b = *(const f16x8*)(buf + (tn * 16 + ln) * LDST + kt * 32 + g * 8);
            acc[0][tn] = MFMA16(a0, b, acc[0][tn]);
            acc[1][tn] = MFMA16(a1, b, acc[1][tn]);
        }
    }
    __syncthreads();

    // epilogue2: h = c + b2 -> buf[row][outfeat] f16 (walk layout)
#pragma unroll
    for (int a = 0; a < 2; ++a) {
        int tm = tm0 + a;
        float4 bv = *(const float4*)(b2 + tm * 16 + g * 4);
#pragma unroll
        for (int tn = 0; tn < 8; ++tn) {
            f32x4 c = acc[a][tn];
            f16x4 h;
            h[0] = (f16)(c[0] + bv.x);
            h[1] = (f16)(c[1] + bv.y);
            h[2] = (f16)(c[2] + bv.z);
            h[3] = (f16)(c[3] + bv.w);
            *(f16x4*)(buf + (tn * 16 + ln) * LDST + tm * 16 + g * 4) = h;
        }
    }
    __syncthreads();

    // sorted-segment walk: thread = (column n, half); one atomic per run per column.
    // Fixed 64-trip count (invalid rows staged as 0 with seg=-1 sentinel), grouped
    // 8x8 with explicit prefetch so the LDS reads batch up instead of serializing
    // behind the data-dependent flush branch.
    int n = tid & 127, half = tid >> 7;
    int m0 = half * 64;
    float accv = 0.f, cnt = 0.f;
    int cur = seg_s[m0];
#pragma unroll
    for (int grp = 0; grp < 8; ++grp) {
        float v[8];
        int s[8];
#pragma unroll
        for (int j = 0; j < 8; ++j) {
            int m = m0 + grp * 8 + j;
            s[j] = seg_s[m];
            v[j] = (float)buf[m * LDST + n];
        }
#pragma unroll
        for (int j = 0; j < 8; ++j) {
            if (s[j] != cur) {
                if (cur >= 0) {
                    atomicAdd(seg_sum + (size_t)cur * DIM + n, accv);
                    if (n == 0) atomicAdd(counts + cur, cnt);
                }
                accv = 0.f; cnt = 0.f; cur = s[j];
            }
            accv += v[j]; cnt += 1.f;
        }
    }
    if (cur >= 0) {
        atomicAdd(seg_sum + (size_t)cur * DIM + n, accv);
        if (n == 0) atomicAdd(counts + cur, cnt);
    }
}

// ---------------- rho MLP on segment means (IN-PLACE: seg_sum aliases out) ---------
// 64-row tiles -> 782 blocks (vs 391) so the latency-bound tail fills the machine.
#define RROWS 64
__global__ __launch_bounds__(256, 4)
void rho_kernel(const float* __restrict__ seg_sum, const float* __restrict__ counts,
                const f16* __restrict__ pack1, const f16* __restrict__ pack2,
                const float* __restrict__ b1, const float* __restrict__ b2,
                float* __restrict__ out) {
    __shared__ f16 buf[RROWS * LDST];  // 17,408 B

    int tid = threadIdx.x;
    int wave = tid >> 6, lane = tid & 63, g = lane >> 4, ln = lane & 15;
    int s0 = blockIdx.x * RROWS;
    int nvalid = min(RROWS, NSEG - s0);

    // stage seg_mean -> f16 LDS (reads complete before any in-place writes below)
#pragma unroll
    for (int i = 0; i < 8; ++i) {
        int flat = i * 1024 + tid * 4;
        int row = flat >> 7, col = flat & 127;
        float4 v = make_float4(0.f, 0.f, 0.f, 0.f);
        if (row < nvalid) {
            v = *(const float4*)(seg_sum + (size_t)(s0 + row) * DIM + col);
            float inv = 1.f / fmaxf(counts[s0 + row], 1.f);
            v.x *= inv; v.y *= inv; v.z *= inv; v.w *= inv;
        }
        f16x4 h;
        h[0] = (f16)v.x; h[1] = (f16)v.y; h[2] = (f16)v.z; h[3] = (f16)v.w;
        *(f16x4*)(buf + row * LDST + col) = h;
    }
    __syncthreads();

    int tm0 = wave * 2;
    f32x4 acc[2][4];
#pragma unroll
    for (int a = 0; a < 2; ++a)
#pragma unroll
        for (int t = 0; t < 4; ++t) acc[a][t] = (f32x4){0.f, 0.f, 0.f, 0.f};

#pragma unroll
    for (int kt = 0; kt < 4; ++kt) {
        f16x8 a0 = *(const f16x8*)(pack1 + ((size_t)((tm0 + 0) * 4 + kt) * 64 + lane) * 8);
        f16x8 a1 = *(const f16x8*)(pack1 + ((size_t)((tm0 + 1) * 4 + kt) * 64 + lane) * 8);
#pragma unroll
        for (int tn = 0; tn < 4; ++tn) {
            f16x8 b = *(const f16x8*)(buf + (tn * 16 + ln) * LDST + kt * 32 + g * 8);
            acc[0][tn] = MFMA16(a0, b, acc[0][tn]);
            acc[1][tn] = MFMA16(a1, b, acc[1][tn]);
        }
    }
    __syncthreads();

#pragma unroll
    for (int a = 0; a < 2; ++a) {
        int tm = tm0 + a;
        float4 bv = *(const float4*)(b1 + tm * 16 + g * 4);
#pragma unroll
        for (int tn = 0; tn < 4; ++tn) {
            f32x4 c = acc[a][tn];
            f16x4 h;
            h[0] = (f16)fmaxf(c[0] + bv.x, 0.f);
            h[1] = (f16)fmaxf(c[1] + bv.y, 0.f);
            h[2] = (f16)fmaxf(c[2] + bv.z, 0.f);
            h[3] = (f16)fmaxf(c[3] + bv.w, 0.f);
            *(f16x4*)(buf + (tn * 16 + ln) * LDST + tm * 16 + g * 4) = h;
        }
    }
    __syncthreads();

#pragma unroll
    for (int a = 0; a < 2; ++a)
#pragma unroll
        for (int t = 0; t < 4; ++t) acc[a][t] = (f32x4){0.f, 0.f, 0.f, 0.f};
#pragma unroll
    for (int kt = 0; kt < 4; ++kt) {
        f16x8 a0 = *(const f16x8*)(pack2 + ((size_t)((tm0 + 0) * 4 + kt) * 64 + lane) * 8);
        f16x8 a1 = *(const f16x8*)(pack2 + ((size_t)((tm0 + 1) * 4 + kt) * 64 + lane) * 8);
#pragma unroll
        for (int tn = 0; tn < 4; ++tn) {
            f16x8 b = *(const f16x8*)(buf + (tn * 16 + ln) * LDST + kt * 32 + g * 8);
            acc[0][tn] = MFMA16(a0, b, acc[0][tn]);
            acc[1][tn] = MFMA16(a1, b, acc[1][tn]);
        }
    }

    // epilogue: out[s][feat] = c + b2, coalesced float4 stores (in-place over seg_sum)
#pragma unroll
    for (int a = 0; a < 2; ++a) {
        int tm = tm0 + a;
        float4 bv = *(const float4*)(b2 + tm * 16 + g * 4);
#pragma unroll
        for (int tn = 0; tn < 4; ++tn) {
            int srow = tn * 16 + ln;
            if (s0 + srow < NSEG) {
                f32x4 c = acc[a][tn];
                float4 o = make_float4(c[0] + bv.x, c[1] + bv.y, c[2] + bv.z, c[3] + bv.w);
                *(float4*)(out + (size_t)(s0 + srow) * DIM + tm * 16 + g * 4) = o;
            }
        }
    }
}

extern "C" void kernel_launch(void* const* d_in, const int* in_sizes, int n_in,
                              void* d_out, int out_size, void* d_ws, size_t ws_size,
                              hipStream_t stream) {
    const float* ins = (const float*)d_in[0];
    const int* batch = (const int*)d_in[1];   // harness delivers integer inputs as int32
    // d_in[2] = dim (unused, always 0)
    const float* phi_W1 = (const float*)d_in[3];
    const float* phi_b1 = (const float*)d_in[4];
    const float* phi_W2 = (const float*)d_in[5];
    const float* phi_b2 = (const float*)d_in[6];
    const float* rho_W1 = (const float*)d_in[7];
    const float* rho_b1 = (const float*)d_in[8];
    const float* rho_W2 = (const float*)d_in[9];
    const float* rho_b2 = (const float*)d_in[10];

    int N = in_sizes[0] / DIM;  // 1,000,000

    // seg_sum lives IN d_out (50000*128 fp32 = 25.6 MB): rho_kernel stages each
    // 64-row tile to LDS before overwriting the same rows -> in-place safe.
    float* seg_sum = (float*)d_out;
    char* ws = (char*)d_ws;
    float* counts = (float*)ws;           // 200,000 B
    f16*   packs  = (f16*)(ws + 200704);  // 4 * 32,768 B; total ws use ~331 KB

    // zero accumulators via one kernel (graph-capture-safe)
    int n4a = NSEG * DIM / 4;   // 1,600,000
    int n4b = NSEG / 4;         // 12,500
    zero2_kernel<<<(n4a + n4b + 255) / 256, 256, 0, stream>>>((float4*)seg_sum, n4a,
                                                              (float4*)counts, n4b);

    prepack_kernel<<<32, 256, 0, stream>>>(phi_W1, phi_W2, rho_W1, rho_W2, packs);

    int nblk = (N + 127) / 128;
    phi_scatter_kernel<<<nblk, 256, 0, stream>>>(ins, batch, packs, packs + 16384,
                                                 phi_b1, phi_b2, seg_sum, counts, N);

    rho_kernel<<<(NSEG + RROWS - 1) / RROWS, 256, 0, stream>>>(seg_sum, counts,
                                                       packs + 2 * 16384, packs + 3 * 16384,
                                                       rho_b1, rho_b2, (float*)d_out);
}